// Round 1
// baseline (536.914 us; speedup 1.0000x reference)
//
#include <hip/hip_runtime.h>

// Problem constants
#define BB 4
#define LL 2048
#define DD 1024
#define NH 16
#define DH 64
#define MM (BB*LL)   // 8192 rows

typedef _Float16 half8 __attribute__((ext_vector_type(8)));
typedef _Float16 half4 __attribute__((ext_vector_type(4)));
typedef float floatx4 __attribute__((ext_vector_type(4)));

__device__ __forceinline__ void gload_lds16(const void* g, void* l) {
    __builtin_amdgcn_global_load_lds((const __attribute__((address_space(1))) void*)g,
                                     (__attribute__((address_space(3))) void*)l,
                                     16, 0, 0);
}

__device__ __forceinline__ floatx4 mfma16(half8 a, half8 b, floatx4 c) {
    return __builtin_amdgcn_mfma_f32_16x16x32_f16(a, b, c, 0, 0, 0);
}

// ---------------- fp32 -> fp16 convert ----------------
__global__ __launch_bounds__(256) void cvt_f32_f16(const float* __restrict__ s,
                                                   _Float16* __restrict__ d, int n4) {
    int i = blockIdx.x * 256 + threadIdx.x;
    if (i < n4) {
        float4 f = ((const float4*)s)[i];
        half4 h;
        h[0] = (_Float16)f.x; h[1] = (_Float16)f.y;
        h[2] = (_Float16)f.z; h[3] = (_Float16)f.w;
        ((half4*)d)[i] = h;
    }
}

// ---------------- GEMM: C[M,N] = A[M,K] * W[N,K]^T + bias ----------------
// m97-style: 128x128 tile, BK=32, global_load_lds(16B), 16x16x32 fp16 MFMA
template <typename OutT>
__global__ __launch_bounds__(256) void gemm_nt(const _Float16* __restrict__ A,
                                               const _Float16* __restrict__ W,
                                               const float* __restrict__ bias,
                                               OutT* __restrict__ C) {
    const int K = 1024, N = 1024;
    __shared__ _Float16 As[128 * 32];
    __shared__ _Float16 Bs[128 * 32];

    int tid = threadIdx.x;
    int wave = tid >> 6, lane = tid & 63;
    int quad = lane >> 4, l15 = lane & 15;
    int wrow = (wave >> 1) * 64, wcol = (wave & 1) * 64;
    int m0 = blockIdx.y * 128;
    int n0 = blockIdx.x * 128;

    floatx4 acc[4][4] = {};

    // staging pointers: thread t covers row=t>>2 (+64 on pass1), seg=t&3 (8 halfs)
    int srow = tid >> 2, sseg = tid & 3;
    const _Float16* Ag0 = A + (size_t)(m0 + srow) * K + sseg * 8;
    const _Float16* Ag1 = Ag0 + (size_t)64 * K;
    const _Float16* Bg0 = W + (size_t)(n0 + srow) * K + sseg * 8;
    const _Float16* Bg1 = Bg0 + (size_t)64 * K;
    char* ldsA0 = (char*)As + tid * 16;
    char* ldsA1 = (char*)As + (256 + tid) * 16;
    char* ldsB0 = (char*)Bs + tid * 16;
    char* ldsB1 = (char*)Bs + (256 + tid) * 16;

    for (int kt = 0; kt < K; kt += 32) {
        __syncthreads();
        gload_lds16(Ag0 + kt, ldsA0);
        gload_lds16(Ag1 + kt, ldsA1);
        gload_lds16(Bg0 + kt, ldsB0);
        gload_lds16(Bg1 + kt, ldsB1);
        __syncthreads();

        half8 af[4], bf[4];
#pragma unroll
        for (int i = 0; i < 4; i++)
            af[i] = *(half8*)&As[(wrow + i * 16 + l15) * 32 + quad * 8];
#pragma unroll
        for (int j = 0; j < 4; j++)
            bf[j] = *(half8*)&Bs[(wcol + j * 16 + l15) * 32 + quad * 8];
#pragma unroll
        for (int i = 0; i < 4; i++)
#pragma unroll
            for (int j = 0; j < 4; j++)
                acc[i][j] = mfma16(af[i], bf[j], acc[i][j]);
    }

    // epilogue: bias + store.  C/D layout: col = l15, row = quad*4 + r
#pragma unroll
    for (int j = 0; j < 4; j++) {
        int col = n0 + wcol + j * 16 + l15;
        float bv = bias[col];
#pragma unroll
        for (int i = 0; i < 4; i++) {
#pragma unroll
            for (int r = 0; r < 4; r++) {
                int row = m0 + wrow + i * 16 + quad * 4 + r;
                float v = acc[i][j][r] + bv;
                C[(size_t)row * N + col] = (OutT)v;
            }
        }
    }
}

// ---------------- L2 normalize over contiguous 64-element head groups ----------------
__global__ __launch_bounds__(256) void l2norm_k(_Float16* __restrict__ Qp,
                                                _Float16* __restrict__ Kp) {
    _Float16* X = blockIdx.y ? Kp : Qp;
    size_t i = ((size_t)blockIdx.x * 256 + threadIdx.x) * 8;  // 8 halfs/thread, 8 threads/group
    half8 v = *(half8*)(X + i);
    float f[8];
    float s = 0.f;
#pragma unroll
    for (int j = 0; j < 8; j++) { f[j] = (float)v[j]; s += f[j] * f[j]; }
    s += __shfl_xor(s, 1);
    s += __shfl_xor(s, 2);
    s += __shfl_xor(s, 4);
    float sc = 1.0f / fmaxf(sqrtf(s), 1e-12f);
#pragma unroll
    for (int j = 0; j < 8; j++) v[j] = (_Float16)(f[j] * sc);
    *(half8*)(X + i) = v;
}

// ---------------- fused cosine attention (no-max streaming softmax) ----------------
// grid: (L/64, B*H).  Block: 256 thr = 4 waves; wave w owns Q-rows w*16..w*16+15.
#define LP 88  // padded LDS row (halfs): 176B, 16B-aligned, bank-stride 12 -> 2-way only
__global__ __launch_bounds__(256) void attn_k(const _Float16* __restrict__ Q,
                                              const _Float16* __restrict__ K,
                                              const _Float16* __restrict__ V,
                                              _Float16* __restrict__ Mg) {
    __shared__ _Float16 Qs[64 * LP];
    __shared__ _Float16 Ks[64 * LP];
    __shared__ _Float16 Vt[64 * LP];  // Vt[dh][key]
    __shared__ _Float16 Ps[64 * LP];  // P[qrow][key]
    __shared__ float lsum[64];

    const float C2 = 20.60992915555662f;  // log2(e)/0.07
    const float OFF = 6.0f;               // exponent bias so P fits fp16

    int tid = threadIdx.x, wave = tid >> 6, lane = tid & 63;
    int quad = lane >> 4, l15 = lane & 15;
    int bh = blockIdx.y;
    int b = bh >> 4, h = bh & 15;
    int q0 = blockIdx.x * 64;
    size_t rowBase = (size_t)b * LL;
    int colBase = h * 64;
    int wq0 = wave * 16;

    // stage Q tile (once): rows q0..q0+63, cols colBase..+63 -> padded Qs
#pragma unroll
    for (int p = 0; p < 2; p++) {
        int c = p * 256 + tid;
        int r = c >> 3, s = c & 7;
        half8 d = *(const half8*)(Q + (rowBase + q0 + r) * DD + colBase + s * 8);
        *(half8*)&Qs[r * LP + s * 8] = d;
    }
    if (tid < 64) lsum[tid] = 0.f;

    floatx4 oacc[4] = {};

    for (int kt0 = 0; kt0 < LL; kt0 += 64) {
        __syncthreads();  // protect Ks/Vt vs previous iteration's reads
        // stage K tile
#pragma unroll
        for (int p = 0; p < 2; p++) {
            int c = p * 256 + tid;
            int r = c >> 3, s = c & 7;
            half8 d = *(const half8*)(K + (rowBase + kt0 + r) * DD + colBase + s * 8);
            *(half8*)&Ks[r * LP + s * 8] = d;
        }
        // stage V transposed: lanes span keys for LDS-conflict-free scatter
#pragma unroll
        for (int p = 0; p < 2; p++) {
            int c = p * 256 + tid;
            int key = c & 63, ds8 = c >> 6;
            half8 d = *(const half8*)(V + (rowBase + kt0 + key) * DD + colBase + ds8 * 8);
#pragma unroll
            for (int j = 0; j < 8; j++) Vt[(ds8 * 8 + j) * LP + key] = d[j];
        }
        __syncthreads();

        // S = Q*K^T for this wave's 16 rows x 64 keys
        floatx4 s[4] = {};
#pragma unroll
        for (int ks = 0; ks < 2; ks++) {
            half8 a = *(half8*)&Qs[(wq0 + l15) * LP + ks * 32 + quad * 8];
#pragma unroll
            for (int j = 0; j < 4; j++) {
                half8 bfr = *(half8*)&Ks[(j * 16 + l15) * LP + ks * 32 + quad * 8];
                s[j] = mfma16(a, bfr, s[j]);
            }
        }

        // P = exp2(s*C2 - OFF); row sums; write P to LDS (wave-exclusive rows)
        float rs[4] = {0.f, 0.f, 0.f, 0.f};
#pragma unroll
        for (int j = 0; j < 4; j++) {
#pragma unroll
            for (int r = 0; r < 4; r++) {
                float e = exp2f(s[j][r] * C2 - OFF);
                _Float16 ph = (_Float16)e;
                Ps[(wq0 + quad * 4 + r) * LP + j * 16 + l15] = ph;
                rs[r] += (float)ph;  // sum the rounded value (matches PV numerator)
            }
        }
#pragma unroll
        for (int r = 0; r < 4; r++) {
            float v = rs[r];
            v += __shfl_xor(v, 1);
            v += __shfl_xor(v, 2);
            v += __shfl_xor(v, 4);
            v += __shfl_xor(v, 8);
            if (l15 == 0) lsum[wq0 + quad * 4 + r] += v;
        }

        // O += P*V  (A from Ps own rows, B from Vt)
#pragma unroll
        for (int ks = 0; ks < 2; ks++) {
            half8 a = *(half8*)&Ps[(wq0 + l15) * LP + ks * 32 + quad * 8];
#pragma unroll
            for (int j = 0; j < 4; j++) {
                half8 bfr = *(half8*)&Vt[(j * 16 + l15) * LP + ks * 32 + quad * 8];
                oacc[j] = mfma16(a, bfr, oacc[j]);
            }
        }
    }

    // epilogue: normalize by lsum, write merged [row][h*64+dh] fp16
#pragma unroll
    for (int r = 0; r < 4; r++) {
        float inv = 1.0f / lsum[wq0 + quad * 4 + r];
#pragma unroll
        for (int j = 0; j < 4; j++) {
            float v = oacc[j][r] * inv;
            Mg[(rowBase + q0 + wq0 + quad * 4 + r) * DD + colBase + j * 16 + l15] = (_Float16)v;
        }
    }
}

// ---------------- launch ----------------
extern "C" void kernel_launch(void* const* d_in, const int* in_sizes, int n_in,
                              void* d_out, int out_size, void* d_ws, size_t ws_size,
                              hipStream_t stream) {
    (void)in_sizes; (void)n_in; (void)out_size; (void)ws_size;
    const float* q  = (const float*)d_in[0];
    const float* k  = (const float*)d_in[1];
    const float* v  = (const float*)d_in[2];
    const float* Wq = (const float*)d_in[3];
    const float* bq = (const float*)d_in[4];
    const float* Wk = (const float*)d_in[5];
    const float* bk = (const float*)d_in[6];
    const float* Wv = (const float*)d_in[7];
    const float* bv = (const float*)d_in[8];
    const float* Wo = (const float*)d_in[9];
    const float* bo = (const float*)d_in[10];

    const size_t NQKV = (size_t)MM * DD;  // 8388608
    const size_t NW = (size_t)DD * DD;    // 1048576

    _Float16* q16  = (_Float16*)d_ws;
    _Float16* k16  = q16 + NQKV;
    _Float16* v16  = k16 + NQKV;
    _Float16* wq16 = v16 + NQKV;
    _Float16* wk16 = wq16 + NW;
    _Float16* wv16 = wk16 + NW;
    _Float16* wo16 = wv16 + NW;
    _Float16* Qp   = wo16 + NW;
    _Float16* Kp   = Qp + NQKV;
    _Float16* Vp   = Kp + NQKV;
    _Float16* Mg   = Vp + NQKV;

    // converts
    cvt_f32_f16<<<dim3(NQKV / 4 / 256), dim3(256), 0, stream>>>(q, q16, NQKV / 4);
    cvt_f32_f16<<<dim3(NQKV / 4 / 256), dim3(256), 0, stream>>>(k, k16, NQKV / 4);
    cvt_f32_f16<<<dim3(NQKV / 4 / 256), dim3(256), 0, stream>>>(v, v16, NQKV / 4);
    cvt_f32_f16<<<dim3(NW / 4 / 256), dim3(256), 0, stream>>>(Wq, wq16, NW / 4);
    cvt_f32_f16<<<dim3(NW / 4 / 256), dim3(256), 0, stream>>>(Wk, wk16, NW / 4);
    cvt_f32_f16<<<dim3(NW / 4 / 256), dim3(256), 0, stream>>>(Wv, wv16, NW / 4);
    cvt_f32_f16<<<dim3(NW / 4 / 256), dim3(256), 0, stream>>>(Wo, wo16, NW / 4);

    // projections: [8192,1024] x [1024,1024]^T + bias -> fp16
    dim3 ggrid(1024 / 128, MM / 128);
    gemm_nt<_Float16><<<ggrid, dim3(256), 0, stream>>>(q16, wq16, bq, Qp);
    gemm_nt<_Float16><<<ggrid, dim3(256), 0, stream>>>(k16, wk16, bk, Kp);
    gemm_nt<_Float16><<<ggrid, dim3(256), 0, stream>>>(v16, wv16, bv, Vp);

    // L2 normalize Q,K per 64-el head group
    l2norm_k<<<dim3(NQKV / 8 / 256, 2), dim3(256), 0, stream>>>(Qp, Kp);

    // fused attention -> merged fp16
    attn_k<<<dim3(LL / 64, BB * NH), dim3(256), 0, stream>>>(Qp, Kp, Vp, Mg);

    // output projection -> fp32 d_out
    gemm_nt<float><<<ggrid, dim3(256), 0, stream>>>(Mg, wo16, bo, (float*)d_out);
}

// Round 3
// 400.780 us; speedup vs baseline: 1.3397x; 1.3397x over previous
//
#include <hip/hip_runtime.h>

// Problem constants
#define BB 4
#define LL 2048
#define DD 1024
#define NH 16
#define DH 64
#define MM (BB*LL)   // 8192 rows

typedef _Float16 half8 __attribute__((ext_vector_type(8)));
typedef _Float16 half4 __attribute__((ext_vector_type(4)));
typedef _Float16 half2 __attribute__((ext_vector_type(2)));
typedef float floatx4 __attribute__((ext_vector_type(4)));

__device__ __forceinline__ void gload_lds16(const void* g, void* l) {
    __builtin_amdgcn_global_load_lds((const __attribute__((address_space(1))) void*)g,
                                     (__attribute__((address_space(3))) void*)l,
                                     16, 0, 0);
}

__device__ __forceinline__ floatx4 mfma16(half8 a, half8 b, floatx4 c) {
    return __builtin_amdgcn_mfma_f32_16x16x32_f16(a, b, c, 0, 0, 0);
}

// ---------------- fp32 -> fp16 convert ----------------
__global__ __launch_bounds__(256) void cvt_f32_f16(const float* __restrict__ s,
                                                   _Float16* __restrict__ d, int n4) {
    int i = blockIdx.x * 256 + threadIdx.x;
    if (i < n4) {
        float4 f = ((const float4*)s)[i];
        half4 h;
        h[0] = (_Float16)f.x; h[1] = (_Float16)f.y;
        h[2] = (_Float16)f.z; h[3] = (_Float16)f.w;
        ((half4*)d)[i] = h;
    }
}

// ---------------- GEMM: C[M,N] = A[M,K] * W[N,K]^T + bias ----------------
template <typename OutT>
__global__ __launch_bounds__(256) void gemm_nt(const _Float16* __restrict__ A,
                                               const _Float16* __restrict__ W,
                                               const float* __restrict__ bias,
                                               OutT* __restrict__ C) {
    const int K = 1024, N = 1024;
    __shared__ _Float16 As[128 * 32];
    __shared__ _Float16 Bs[128 * 32];

    int tid = threadIdx.x;
    int wave = tid >> 6, lane = tid & 63;
    int quad = lane >> 4, l15 = lane & 15;
    int wrow = (wave >> 1) * 64, wcol = (wave & 1) * 64;
    int m0 = blockIdx.y * 128;
    int n0 = blockIdx.x * 128;

    floatx4 acc[4][4] = {};

    int srow = tid >> 2, sseg = tid & 3;
    const _Float16* Ag0 = A + (size_t)(m0 + srow) * K + sseg * 8;
    const _Float16* Ag1 = Ag0 + (size_t)64 * K;
    const _Float16* Bg0 = W + (size_t)(n0 + srow) * K + sseg * 8;
    const _Float16* Bg1 = Bg0 + (size_t)64 * K;
    char* ldsA0 = (char*)As + tid * 16;
    char* ldsA1 = (char*)As + (256 + tid) * 16;
    char* ldsB0 = (char*)Bs + tid * 16;
    char* ldsB1 = (char*)Bs + (256 + tid) * 16;

    for (int kt = 0; kt < K; kt += 32) {
        __syncthreads();
        gload_lds16(Ag0 + kt, ldsA0);
        gload_lds16(Ag1 + kt, ldsA1);
        gload_lds16(Bg0 + kt, ldsB0);
        gload_lds16(Bg1 + kt, ldsB1);
        __syncthreads();

        half8 af[4], bf[4];
#pragma unroll
        for (int i = 0; i < 4; i++)
            af[i] = *(half8*)&As[(wrow + i * 16 + l15) * 32 + quad * 8];
#pragma unroll
        for (int j = 0; j < 4; j++)
            bf[j] = *(half8*)&Bs[(wcol + j * 16 + l15) * 32 + quad * 8];
#pragma unroll
        for (int i = 0; i < 4; i++)
#pragma unroll
            for (int j = 0; j < 4; j++)
                acc[i][j] = mfma16(af[i], bf[j], acc[i][j]);
    }

#pragma unroll
    for (int j = 0; j < 4; j++) {
        int col = n0 + wcol + j * 16 + l15;
        float bv = bias[col];
#pragma unroll
        for (int i = 0; i < 4; i++) {
#pragma unroll
            for (int r = 0; r < 4; r++) {
                int row = m0 + wrow + i * 16 + quad * 4 + r;
                float v = acc[i][j][r] + bv;
                C[(size_t)row * N + col] = (OutT)v;
            }
        }
    }
}

// ---------------- V GEMM writing transposed per-head output ----------------
// VtG layout: [(b*16+h)*64 + dh][L]  (row length LL=2048 keys)
__global__ __launch_bounds__(256) void gemm_nt_vt(const _Float16* __restrict__ A,
                                                  const _Float16* __restrict__ W,
                                                  const float* __restrict__ bias,
                                                  _Float16* __restrict__ VtG) {
    const int K = 1024;
    __shared__ _Float16 As[128 * 32];
    __shared__ _Float16 Bs[128 * 32];

    int tid = threadIdx.x;
    int wave = tid >> 6, lane = tid & 63;
    int quad = lane >> 4, l15 = lane & 15;
    int wrow = (wave >> 1) * 64, wcol = (wave & 1) * 64;
    int m0 = blockIdx.y * 128;
    int n0 = blockIdx.x * 128;

    floatx4 acc[4][4] = {};

    int srow = tid >> 2, sseg = tid & 3;
    const _Float16* Ag0 = A + (size_t)(m0 + srow) * K + sseg * 8;
    const _Float16* Ag1 = Ag0 + (size_t)64 * K;
    const _Float16* Bg0 = W + (size_t)(n0 + srow) * K + sseg * 8;
    const _Float16* Bg1 = Bg0 + (size_t)64 * K;
    char* ldsA0 = (char*)As + tid * 16;
    char* ldsA1 = (char*)As + (256 + tid) * 16;
    char* ldsB0 = (char*)Bs + tid * 16;
    char* ldsB1 = (char*)Bs + (256 + tid) * 16;

    for (int kt = 0; kt < K; kt += 32) {
        __syncthreads();
        gload_lds16(Ag0 + kt, ldsA0);
        gload_lds16(Ag1 + kt, ldsA1);
        gload_lds16(Bg0 + kt, ldsB0);
        gload_lds16(Bg1 + kt, ldsB1);
        __syncthreads();

        half8 af[4], bf[4];
#pragma unroll
        for (int i = 0; i < 4; i++)
            af[i] = *(half8*)&As[(wrow + i * 16 + l15) * 32 + quad * 8];
#pragma unroll
        for (int j = 0; j < 4; j++)
            bf[j] = *(half8*)&Bs[(wcol + j * 16 + l15) * 32 + quad * 8];
#pragma unroll
        for (int i = 0; i < 4; i++)
#pragma unroll
            for (int j = 0; j < 4; j++)
                acc[i][j] = mfma16(af[i], bf[j], acc[i][j]);
    }

    // epilogue: scatter-store transposed: col -> (h,dh) row, row -> (b,l) col
#pragma unroll
    for (int j = 0; j < 4; j++) {
        int col = n0 + wcol + j * 16 + l15;   // h*64+dh
        float bv = bias[col];
#pragma unroll
        for (int i = 0; i < 4; i++) {
#pragma unroll
            for (int r = 0; r < 4; r++) {
                int row = m0 + wrow + i * 16 + quad * 4 + r;  // b*2048 + l
                int b = row >> 11, l = row & 2047;
                VtG[((size_t)((b << 10) + col)) * LL + l] = (_Float16)(acc[i][j][r] + bv);
            }
        }
    }
}

// ---------------- L2 normalize over contiguous 64-element head groups ----------------
__global__ __launch_bounds__(256) void l2norm_k(_Float16* __restrict__ Qp,
                                                _Float16* __restrict__ Kp) {
    _Float16* X = blockIdx.y ? Kp : Qp;
    size_t i = ((size_t)blockIdx.x * 256 + threadIdx.x) * 8;
    half8 v = *(half8*)(X + i);
    float f[8];
    float s = 0.f;
#pragma unroll
    for (int j = 0; j < 8; j++) { f[j] = (float)v[j]; s += f[j] * f[j]; }
    s += __shfl_xor(s, 1);
    s += __shfl_xor(s, 2);
    s += __shfl_xor(s, 4);
    float sc = 1.0f / fmaxf(sqrtf(s), 1e-12f);
#pragma unroll
    for (int j = 0; j < 8; j++) v[j] = (_Float16)(f[j] * sc);
    *(half8*)(X + i) = v;
}

// ---------------- fused cosine attention v2 ----------------
// grid: (L/128, B*H). 256 thr = 4 waves; wave w owns queries w*32..w*32+31.
// LDS: Ks[64key][64dh] xor-swizzled, Vt[64dh][64key] xor-swizzled,
//      Ps[128q][64key] xor-swizzled, lsum[128].
// S^T = K*Q^T (MFMA), exp -> pkrtz -> b64 write, O = P*V^T-frags.
__global__ __launch_bounds__(256) void attn_k(const _Float16* __restrict__ Q,
                                              const _Float16* __restrict__ K,
                                              const _Float16* __restrict__ VtG,
                                              _Float16* __restrict__ Mg) {
    __shared__ _Float16 Ks[64 * 64];
    __shared__ _Float16 Vt[64 * 64];
    __shared__ _Float16 Ps[128 * 64];
    __shared__ float lsum[128];

    const float C2 = 20.60992915555662f;  // log2(e)/0.07
    const float OFF = 6.0f;

    int tid = threadIdx.x, wave = tid >> 6, lane = tid & 63;
    int quad = lane >> 4, l15 = lane & 15;
    int bh = blockIdx.y;
    int b = bh >> 4, h = bh & 15;
    int q0 = blockIdx.x * 128;
    size_t rowBase = (size_t)b * LL;
    int colBase = h * 64;
    int wq = wave * 32;
    int sw = l15 & 7;  // xor-swizzle key for this lane's fragment rows

    // ---- Q fragments: direct global gather, held in regs all kernel ----
    half8 qf[2][2];  // [ib][ks]
#pragma unroll
    for (int ib = 0; ib < 2; ib++)
#pragma unroll
        for (int ks = 0; ks < 2; ks++)
            qf[ib][ks] = *(const half8*)(Q + (rowBase + q0 + wq + ib * 16 + l15) * DD +
                                         colBase + ks * 32 + quad * 8);

    // ---- staging pointers (2 K-slots + 2 Vt-slots per thread) ----
    const _Float16* kg[2];
    const _Float16* vg[2];
    char* kl[2];
    char* vl[2];
#pragma unroll
    for (int p = 0; p < 2; p++) {
        int s = p * 256 + tid;
        int r = s >> 3, cs = s & 7;
        int ck = cs ^ (r & 7);
        kg[p] = K + (rowBase + r) * DD + colBase + ck * 8;   // advance 64*DD per tile
        kl[p] = (char*)Ks + s * 16;
        vg[p] = VtG + ((size_t)bh * 64 + r) * LL + ck * 8;   // advance 64 per tile
        vl[p] = (char*)Vt + s * 16;
    }

    floatx4 oacc[2][4] = {};  // [ib][jb(dh)]
    float fsum[2] = {0.f, 0.f};

    for (int kt = 0; kt < LL; kt += 64) {
        __syncthreads();
        gload_lds16(kg[0], kl[0]); kg[0] += 64 * DD;
        gload_lds16(kg[1], kl[1]); kg[1] += 64 * DD;
        gload_lds16(vg[0], vl[0]); vg[0] += 64;
        gload_lds16(vg[1], vl[1]); vg[1] += 64;
        __syncthreads();

        // ---- S^T = K * Q^T : D[key][q] ----
        floatx4 st[2][4] = {};  // [ib][jb(key block)]
#pragma unroll
        for (int ks = 0; ks < 2; ks++) {
            half8 kf[4];
#pragma unroll
            for (int jb = 0; jb < 4; jb++)
                kf[jb] = *(half8*)&Ks[(jb * 16 + l15) * 64 + (((ks * 4 + quad) ^ sw) * 8)];
#pragma unroll
            for (int ib = 0; ib < 2; ib++)
#pragma unroll
                for (int jb = 0; jb < 4; jb++)
                    st[ib][jb] = mfma16(kf[jb], qf[ib][ks], st[ib][jb]);
        }

        // ---- P = exp2(s*C2-OFF) ; pack 4 consecutive keys -> b64 write ----
#pragma unroll
        for (int ib = 0; ib < 2; ib++) {
#pragma unroll
            for (int jb = 0; jb < 4; jb++) {
                float e0 = __builtin_amdgcn_exp2f(st[ib][jb][0] * C2 - OFF);
                float e1 = __builtin_amdgcn_exp2f(st[ib][jb][1] * C2 - OFF);
                float e2 = __builtin_amdgcn_exp2f(st[ib][jb][2] * C2 - OFF);
                float e3 = __builtin_amdgcn_exp2f(st[ib][jb][3] * C2 - OFF);
                fsum[ib] += (e0 + e1) + (e2 + e3);
                half2 p01 = __builtin_bit_cast(half2, __builtin_amdgcn_cvt_pkrtz(e0, e1));
                half2 p23 = __builtin_bit_cast(half2, __builtin_amdgcn_cvt_pkrtz(e2, e3));
                half4 pk; pk[0] = p01[0]; pk[1] = p01[1]; pk[2] = p23[0]; pk[3] = p23[1];
                int chunk = (jb * 2 + (quad >> 1)) ^ sw;
                *(half4*)((char*)Ps + (wq + ib * 16 + l15) * 128 + chunk * 16 + (quad & 1) * 8) = pk;
            }
        }

        // ---- O += P * V^T-frags ----
#pragma unroll
        for (int kb = 0; kb < 2; kb++) {
            half8 pf[2];
#pragma unroll
            for (int ib = 0; ib < 2; ib++)
                pf[ib] = *(half8*)&Ps[(wq + ib * 16 + l15) * 64 + (((kb * 4 + quad) ^ sw) * 8)];
#pragma unroll
            for (int jb = 0; jb < 4; jb++) {
                half8 vf = *(half8*)&Vt[(jb * 16 + l15) * 64 + (((kb * 4 + quad) ^ sw) * 8)];
#pragma unroll
                for (int ib = 0; ib < 2; ib++)
                    oacc[ib][jb] = mfma16(pf[ib], vf, oacc[ib][jb]);
            }
        }
    }

    // ---- epilogue: reduce row sums across quads, exchange via LDS, store ----
#pragma unroll
    for (int ib = 0; ib < 2; ib++) {
        float v = fsum[ib];
        v += __shfl_xor(v, 16);
        v += __shfl_xor(v, 32);
        lsum[wq + ib * 16 + l15] = v;  // all quads write same value: benign
    }
#pragma unroll
    for (int ib = 0; ib < 2; ib++) {
#pragma unroll
        for (int r = 0; r < 4; r++) {
            float inv = 1.0f / lsum[wq + ib * 16 + quad * 4 + r];
            int qrow = q0 + wq + ib * 16 + quad * 4 + r;
#pragma unroll
            for (int jb = 0; jb < 4; jb++) {
                float v = oacc[ib][jb][r] * inv;
                Mg[(rowBase + qrow) * DD + colBase + jb * 16 + l15] = (_Float16)v;
            }
        }
    }
}

// ---------------- launch ----------------
extern "C" void kernel_launch(void* const* d_in, const int* in_sizes, int n_in,
                              void* d_out, int out_size, void* d_ws, size_t ws_size,
                              hipStream_t stream) {
    (void)in_sizes; (void)n_in; (void)out_size; (void)ws_size;
    const float* q  = (const float*)d_in[0];
    const float* k  = (const float*)d_in[1];
    const float* v  = (const float*)d_in[2];
    const float* Wq = (const float*)d_in[3];
    const float* bq = (const float*)d_in[4];
    const float* Wk = (const float*)d_in[5];
    const float* bk = (const float*)d_in[6];
    const float* Wv = (const float*)d_in[7];
    const float* bv = (const float*)d_in[8];
    const float* Wo = (const float*)d_in[9];
    const float* bo = (const float*)d_in[10];

    const size_t NQKV = (size_t)MM * DD;  // 8388608
    const size_t NW = (size_t)DD * DD;    // 1048576

    _Float16* q16  = (_Float16*)d_ws;
    _Float16* k16  = q16 + NQKV;
    _Float16* v16  = k16 + NQKV;
    _Float16* wq16 = v16 + NQKV;
    _Float16* wk16 = wq16 + NW;
    _Float16* wv16 = wk16 + NW;
    _Float16* wo16 = wv16 + NW;
    _Float16* Qp   = wo16 + NW;
    _Float16* Kp   = Qp + NQKV;
    _Float16* VtG  = Kp + NQKV;
    _Float16* Mg   = VtG + NQKV;

    cvt_f32_f16<<<dim3(NQKV / 4 / 256), dim3(256), 0, stream>>>(q, q16, NQKV / 4);
    cvt_f32_f16<<<dim3(NQKV / 4 / 256), dim3(256), 0, stream>>>(k, k16, NQKV / 4);
    cvt_f32_f16<<<dim3(NQKV / 4 / 256), dim3(256), 0, stream>>>(v, v16, NQKV / 4);
    cvt_f32_f16<<<dim3(NW / 4 / 256), dim3(256), 0, stream>>>(Wq, wq16, NW / 4);
    cvt_f32_f16<<<dim3(NW / 4 / 256), dim3(256), 0, stream>>>(Wk, wk16, NW / 4);
    cvt_f32_f16<<<dim3(NW / 4 / 256), dim3(256), 0, stream>>>(Wv, wv16, NW / 4);
    cvt_f32_f16<<<dim3(NW / 4 / 256), dim3(256), 0, stream>>>(Wo, wo16, NW / 4);

    dim3 ggrid(1024 / 128, MM / 128);
    gemm_nt<_Float16><<<ggrid, dim3(256), 0, stream>>>(q16, wq16, bq, Qp);
    gemm_nt<_Float16><<<ggrid, dim3(256), 0, stream>>>(k16, wk16, bk, Kp);
    gemm_nt_vt<<<ggrid, dim3(256), 0, stream>>>(v16, wv16, bv, VtG);

    l2norm_k<<<dim3(NQKV / 8 / 256, 2), dim3(256), 0, stream>>>(Qp, Kp);

    attn_k<<<dim3(LL / 128, BB * NH), dim3(256), 0, stream>>>(Qp, Kp, VtG, Mg);

    gemm_nt<float><<<ggrid, dim3(256), 0, stream>>>(Mg, wo16, bo, (float*)d_out);
}

// Round 5
// 364.654 us; speedup vs baseline: 1.4724x; 1.0991x over previous
//
#include <hip/hip_runtime.h>

// Problem constants
#define BB 4
#define LL 2048
#define DD 1024
#define NH 16
#define DH 64
#define MM (BB*LL)   // 8192 rows

typedef _Float16 half8 __attribute__((ext_vector_type(8)));
typedef _Float16 half4 __attribute__((ext_vector_type(4)));
typedef _Float16 half2 __attribute__((ext_vector_type(2)));
typedef float floatx4 __attribute__((ext_vector_type(4)));

__device__ __forceinline__ void gload_lds16(const void* g, void* l) {
    __builtin_amdgcn_global_load_lds((const __attribute__((address_space(1))) void*)g,
                                     (__attribute__((address_space(3))) void*)l,
                                     16, 0, 0);
}

__device__ __forceinline__ floatx4 mfma16(half8 a, half8 b, floatx4 c) {
    return __builtin_amdgcn_mfma_f32_16x16x32_f16(a, b, c, 0, 0, 0);
}

// ---------------- fused fp32 -> fp16 convert (all 7 tensors, 1 launch) ----------------
// dst is the contiguous ws region: q16,k16,v16,wq16,wk16,wv16,wo16
__global__ __launch_bounds__(256) void cvt_all(const float* __restrict__ q,
                                               const float* __restrict__ k,
                                               const float* __restrict__ v,
                                               const float* __restrict__ Wq,
                                               const float* __restrict__ Wk,
                                               const float* __restrict__ Wv,
                                               const float* __restrict__ Wo,
                                               _Float16* __restrict__ dst) {
    const int BIG = 8192;    // blocks per big tensor (8.39M elems / 1024)
    const int SML = 1024;    // blocks per weight tensor
    const size_t NQKV = (size_t)MM * DD;
    const size_t NW = (size_t)DD * DD;
    int b = blockIdx.x;
    const float* src;
    size_t off;
    int lb;
    if (b < 3 * BIG) {
        int t = b / BIG;
        src = t == 0 ? q : (t == 1 ? k : v);
        off = (size_t)t * NQKV;
        lb = b - t * BIG;
    } else {
        int t = (b - 3 * BIG) / SML;
        src = t == 0 ? Wq : (t == 1 ? Wk : (t == 2 ? Wv : Wo));
        off = 3 * NQKV + (size_t)t * NW;
        lb = b - 3 * BIG - t * SML;
    }
    size_t i = (size_t)lb * 256 + threadIdx.x;
    float4 f = ((const float4*)src)[i];
    half4 h;
    h[0] = (_Float16)f.x; h[1] = (_Float16)f.y;
    h[2] = (_Float16)f.z; h[3] = (_Float16)f.w;
    ((half4*)(dst + off))[i] = h;
}

// ---------------- fused QKV projection GEMM ----------------
// grid (24, 64): bx 0..7 -> Q (+l2norm), 8..15 -> K (+l2norm), 16..23 -> V (transposed store)
// A selected per block from contiguous q16/k16/v16; C = A * W^T + bias.
__global__ __launch_bounds__(256) void gemm_qkv(const _Float16* __restrict__ qkv16,
                                                const _Float16* __restrict__ wq,
                                                const _Float16* __restrict__ wk,
                                                const _Float16* __restrict__ wv,
                                                const float* __restrict__ bq,
                                                const float* __restrict__ bk,
                                                const float* __restrict__ bv,
                                                _Float16* __restrict__ Qp,
                                                _Float16* __restrict__ Kp,
                                                _Float16* __restrict__ VtG) {
    const int K = 1024;
    __shared__ _Float16 As[128 * 32];
    __shared__ _Float16 Bs[128 * 32];

    int tid = threadIdx.x;
    int wave = tid >> 6, lane = tid & 63;
    int quad = lane >> 4, l15 = lane & 15;
    int wrow = (wave >> 1) * 64, wcol = (wave & 1) * 64;
    int bx = blockIdx.x;
    int which = bx >> 3;  // 0=Q, 1=K, 2=V
    int m0 = blockIdx.y * 128;
    int n0 = (bx & 7) * 128;

    const _Float16* A = qkv16 + (size_t)which * ((size_t)MM * DD);  // q16/k16/v16
    const _Float16* W = which == 0 ? wq : (which == 1 ? wk : wv);
    const float* bias = which == 0 ? bq : (which == 1 ? bk : bv);

    floatx4 acc[4][4] = {};

    int srow = tid >> 2, sseg = tid & 3;
    const _Float16* Ag0 = A + (size_t)(m0 + srow) * K + sseg * 8;
    const _Float16* Ag1 = Ag0 + (size_t)64 * K;
    const _Float16* Bg0 = W + (size_t)(n0 + srow) * K + sseg * 8;
    const _Float16* Bg1 = Bg0 + (size_t)64 * K;
    char* ldsA0 = (char*)As + tid * 16;
    char* ldsA1 = (char*)As + (256 + tid) * 16;
    char* ldsB0 = (char*)Bs + tid * 16;
    char* ldsB1 = (char*)Bs + (256 + tid) * 16;

    for (int kt = 0; kt < K; kt += 32) {
        __syncthreads();
        gload_lds16(Ag0 + kt, ldsA0);
        gload_lds16(Ag1 + kt, ldsA1);
        gload_lds16(Bg0 + kt, ldsB0);
        gload_lds16(Bg1 + kt, ldsB1);
        __syncthreads();

        half8 af[4], bf[4];
#pragma unroll
        for (int i = 0; i < 4; i++)
            af[i] = *(half8*)&As[(wrow + i * 16 + l15) * 32 + quad * 8];
#pragma unroll
        for (int j = 0; j < 4; j++)
            bf[j] = *(half8*)&Bs[(wcol + j * 16 + l15) * 32 + quad * 8];
#pragma unroll
        for (int i = 0; i < 4; i++)
#pragma unroll
            for (int j = 0; j < 4; j++)
                acc[i][j] = mfma16(af[i], bf[j], acc[i][j]);
    }

    // add bias (per output col j)
#pragma unroll
    for (int j = 0; j < 4; j++) {
        float bv_ = bias[n0 + wcol + j * 16 + l15];
#pragma unroll
        for (int i = 0; i < 4; i++)
#pragma unroll
            for (int r = 0; r < 4; r++) acc[i][j][r] += bv_;
    }

    if (which < 2) {
        // ---- fused L2 norm: wave's 64-col group == one head ----
        _Float16* C = which == 0 ? Qp : Kp;
#pragma unroll
        for (int i = 0; i < 4; i++) {
#pragma unroll
            for (int r = 0; r < 4; r++) {
                float s = 0.f;
#pragma unroll
                for (int j = 0; j < 4; j++) s += acc[i][j][r] * acc[i][j][r];
                s += __shfl_xor(s, 1);
                s += __shfl_xor(s, 2);
                s += __shfl_xor(s, 4);
                s += __shfl_xor(s, 8);
                float inv = 1.0f / fmaxf(sqrtf(s), 1e-12f);
                int row = m0 + wrow + i * 16 + quad * 4 + r;
#pragma unroll
                for (int j = 0; j < 4; j++) {
                    int col = n0 + wcol + j * 16 + l15;
                    C[(size_t)row * DD + col] = (_Float16)(acc[i][j][r] * inv);
                }
            }
        }
    } else {
        // ---- V: transposed per-head store  VtG[(b*16+h)*64+dh][l] ----
#pragma unroll
        for (int j = 0; j < 4; j++) {
            int col = n0 + wcol + j * 16 + l15;  // h*64+dh
#pragma unroll
            for (int i = 0; i < 4; i++) {
#pragma unroll
                for (int r = 0; r < 4; r++) {
                    int row = m0 + wrow + i * 16 + quad * 4 + r;  // b*2048 + l
                    int b = row >> 11, l = row & 2047;
                    VtG[((size_t)((b << 10) + col)) * LL + l] = (_Float16)acc[i][j][r];
                }
            }
        }
    }
}

// ---------------- output projection GEMM (fp32 out) ----------------
__global__ __launch_bounds__(256) void gemm_out(const _Float16* __restrict__ A,
                                                const _Float16* __restrict__ W,
                                                const float* __restrict__ bias,
                                                float* __restrict__ C) {
    const int K = 1024, N = 1024;
    __shared__ _Float16 As[128 * 32];
    __shared__ _Float16 Bs[128 * 32];

    int tid = threadIdx.x;
    int wave = tid >> 6, lane = tid & 63;
    int quad = lane >> 4, l15 = lane & 15;
    int wrow = (wave >> 1) * 64, wcol = (wave & 1) * 64;
    int m0 = blockIdx.y * 128;
    int n0 = blockIdx.x * 128;

    floatx4 acc[4][4] = {};

    int srow = tid >> 2, sseg = tid & 3;
    const _Float16* Ag0 = A + (size_t)(m0 + srow) * K + sseg * 8;
    const _Float16* Ag1 = Ag0 + (size_t)64 * K;
    const _Float16* Bg0 = W + (size_t)(n0 + srow) * K + sseg * 8;
    const _Float16* Bg1 = Bg0 + (size_t)64 * K;
    char* ldsA0 = (char*)As + tid * 16;
    char* ldsA1 = (char*)As + (256 + tid) * 16;
    char* ldsB0 = (char*)Bs + tid * 16;
    char* ldsB1 = (char*)Bs + (256 + tid) * 16;

    for (int kt = 0; kt < K; kt += 32) {
        __syncthreads();
        gload_lds16(Ag0 + kt, ldsA0);
        gload_lds16(Ag1 + kt, ldsA1);
        gload_lds16(Bg0 + kt, ldsB0);
        gload_lds16(Bg1 + kt, ldsB1);
        __syncthreads();

        half8 af[4], bf[4];
#pragma unroll
        for (int i = 0; i < 4; i++)
            af[i] = *(half8*)&As[(wrow + i * 16 + l15) * 32 + quad * 8];
#pragma unroll
        for (int j = 0; j < 4; j++)
            bf[j] = *(half8*)&Bs[(wcol + j * 16 + l15) * 32 + quad * 8];
#pragma unroll
        for (int i = 0; i < 4; i++)
#pragma unroll
            for (int j = 0; j < 4; j++)
                acc[i][j] = mfma16(af[i], bf[j], acc[i][j]);
    }

#pragma unroll
    for (int j = 0; j < 4; j++) {
        int col = n0 + wcol + j * 16 + l15;
        float bv = bias[col];
#pragma unroll
        for (int i = 0; i < 4; i++) {
#pragma unroll
            for (int r = 0; r < 4; r++) {
                int row = m0 + wrow + i * 16 + quad * 4 + r;
                C[(size_t)row * N + col] = acc[i][j][r] + bv;
            }
        }
    }
}

// ---------------- fused cosine attention ----------------
// grid: (L/128, B*H). 256 thr = 4 waves; wave w owns queries w*32..w*32+31.
__global__ __launch_bounds__(256) void attn_k(const _Float16* __restrict__ Q,
                                              const _Float16* __restrict__ K,
                                              const _Float16* __restrict__ VtG,
                                              _Float16* __restrict__ Mg) {
    __shared__ _Float16 Ks[64 * 64];
    __shared__ _Float16 Vt[64 * 64];
    __shared__ _Float16 Ps[128 * 64];
    __shared__ float lsum[128];

    const float C2 = 20.60992915555662f;  // log2(e)/0.07
    const float OFF = 6.0f;

    int tid = threadIdx.x, wave = tid >> 6, lane = tid & 63;
    int quad = lane >> 4, l15 = lane & 15;
    int bh = blockIdx.y;
    int b = bh >> 4, h = bh & 15;
    int q0 = blockIdx.x * 128;
    size_t rowBase = (size_t)b * LL;
    int colBase = h * 64;
    int wq = wave * 32;
    int sw = l15 & 7;

    half8 qf[2][2];
#pragma unroll
    for (int ib = 0; ib < 2; ib++)
#pragma unroll
        for (int ks = 0; ks < 2; ks++)
            qf[ib][ks] = *(const half8*)(Q + (rowBase + q0 + wq + ib * 16 + l15) * DD +
                                         colBase + ks * 32 + quad * 8);

    const _Float16* kg[2];
    const _Float16* vg[2];
    char* kl[2];
    char* vl[2];
#pragma unroll
    for (int p = 0; p < 2; p++) {
        int s = p * 256 + tid;
        int r = s >> 3, cs = s & 7;
        int ck = cs ^ (r & 7);
        kg[p] = K + (rowBase + r) * DD + colBase + ck * 8;
        kl[p] = (char*)Ks + s * 16;
        vg[p] = VtG + ((size_t)bh * 64 + r) * LL + ck * 8;
        vl[p] = (char*)Vt + s * 16;
    }

    floatx4 oacc[2][4] = {};
    float fsum[2] = {0.f, 0.f};

    for (int kt = 0; kt < LL; kt += 64) {
        __syncthreads();
        gload_lds16(kg[0], kl[0]); kg[0] += 64 * DD;
        gload_lds16(kg[1], kl[1]); kg[1] += 64 * DD;
        gload_lds16(vg[0], vl[0]); vg[0] += 64;
        gload_lds16(vg[1], vl[1]); vg[1] += 64;
        __syncthreads();

        floatx4 st[2][4] = {};
#pragma unroll
        for (int ks = 0; ks < 2; ks++) {
            half8 kf[4];
#pragma unroll
            for (int jb = 0; jb < 4; jb++)
                kf[jb] = *(half8*)&Ks[(jb * 16 + l15) * 64 + (((ks * 4 + quad) ^ sw) * 8)];
#pragma unroll
            for (int ib = 0; ib < 2; ib++)
#pragma unroll
                for (int jb = 0; jb < 4; jb++)
                    st[ib][jb] = mfma16(kf[jb], qf[ib][ks], st[ib][jb]);
        }

#pragma unroll
        for (int ib = 0; ib < 2; ib++) {
#pragma unroll
            for (int jb = 0; jb < 4; jb++) {
                float e0 = __builtin_amdgcn_exp2f(st[ib][jb][0] * C2 - OFF);
                float e1 = __builtin_amdgcn_exp2f(st[ib][jb][1] * C2 - OFF);
                float e2 = __builtin_amdgcn_exp2f(st[ib][jb][2] * C2 - OFF);
                float e3 = __builtin_amdgcn_exp2f(st[ib][jb][3] * C2 - OFF);
                fsum[ib] += (e0 + e1) + (e2 + e3);
                half2 p01 = __builtin_bit_cast(half2, __builtin_amdgcn_cvt_pkrtz(e0, e1));
                half2 p23 = __builtin_bit_cast(half2, __builtin_amdgcn_cvt_pkrtz(e2, e3));
                half4 pk; pk[0] = p01[0]; pk[1] = p01[1]; pk[2] = p23[0]; pk[3] = p23[1];
                int chunk = (jb * 2 + (quad >> 1)) ^ sw;
                *(half4*)((char*)Ps + (wq + ib * 16 + l15) * 128 + chunk * 16 + (quad & 1) * 8) = pk;
            }
        }

#pragma unroll
        for (int kb = 0; kb < 2; kb++) {
            half8 pf[2];
#pragma unroll
            for (int ib = 0; ib < 2; ib++)
                pf[ib] = *(half8*)&Ps[(wq + ib * 16 + l15) * 64 + (((kb * 4 + quad) ^ sw) * 8)];
#pragma unroll
            for (int jb = 0; jb < 4; jb++) {
                half8 vf = *(half8*)&Vt[(jb * 16 + l15) * 64 + (((kb * 4 + quad) ^ sw) * 8)];
#pragma unroll
                for (int ib = 0; ib < 2; ib++)
                    oacc[ib][jb] = mfma16(pf[ib], vf, oacc[ib][jb]);
            }
        }
    }

#pragma unroll
    for (int ib = 0; ib < 2; ib++) {
        float v = fsum[ib];
        v += __shfl_xor(v, 16);
        v += __shfl_xor(v, 32);
        lsum[wq + ib * 16 + l15] = v;
    }
#pragma unroll
    for (int ib = 0; ib < 2; ib++) {
#pragma unroll
        for (int r = 0; r < 4; r++) {
            float inv = 1.0f / lsum[wq + ib * 16 + quad * 4 + r];
            int qrow = q0 + wq + ib * 16 + quad * 4 + r;
#pragma unroll
            for (int jb = 0; jb < 4; jb++) {
                float v = oacc[ib][jb][r] * inv;
                Mg[(rowBase + qrow) * DD + colBase + jb * 16 + l15] = (_Float16)v;
            }
        }
    }
}

// ---------------- launch ----------------
extern "C" void kernel_launch(void* const* d_in, const int* in_sizes, int n_in,
                              void* d_out, int out_size, void* d_ws, size_t ws_size,
                              hipStream_t stream) {
    (void)in_sizes; (void)n_in; (void)out_size; (void)ws_size;
    const float* q  = (const float*)d_in[0];
    const float* k  = (const float*)d_in[1];
    const float* v  = (const float*)d_in[2];
    const float* Wq = (const float*)d_in[3];
    const float* bq = (const float*)d_in[4];
    const float* Wk = (const float*)d_in[5];
    const float* bk = (const float*)d_in[6];
    const float* Wv = (const float*)d_in[7];
    const float* bv = (const float*)d_in[8];
    const float* Wo = (const float*)d_in[9];
    const float* bo = (const float*)d_in[10];

    const size_t NQKV = (size_t)MM * DD;  // 8388608
    const size_t NW = (size_t)DD * DD;    // 1048576

    _Float16* q16  = (_Float16*)d_ws;
    _Float16* k16  = q16 + NQKV;
    _Float16* v16  = k16 + NQKV;
    _Float16* wq16 = v16 + NQKV;
    _Float16* wk16 = wq16 + NW;
    _Float16* wv16 = wk16 + NW;
    _Float16* wo16 = wv16 + NW;
    _Float16* Qp   = wo16 + NW;
    _Float16* Kp   = Qp + NQKV;
    _Float16* VtG  = Kp + NQKV;
    _Float16* Mg   = VtG + NQKV;
    (void)k16; (void)v16;

    // one fused convert: 3*8192 + 4*1024 blocks
    cvt_all<<<dim3(3 * 8192 + 4 * 1024), dim3(256), 0, stream>>>(q, k, v, Wq, Wk, Wv, Wo, q16);

    // fused QKV projection (+l2norm on Q/K, transposed V); A = q16/k16/v16 by block
    gemm_qkv<<<dim3(24, MM / 128), dim3(256), 0, stream>>>(q16, wq16, wk16, wv16,
                                                           bq, bk, bv, Qp, Kp, VtG);

    // fused attention
    attn_k<<<dim3(LL / 128, BB * NH), dim3(256), 0, stream>>>(Qp, Kp, VtG, Mg);

    // output projection -> fp32 d_out
    gemm_out<<<dim3(1024 / 128, MM / 128), dim3(256), 0, stream>>>(Mg, wo16, bo, (float*)d_out);
}